// Round 4
// baseline (1228.665 us; speedup 1.0000x reference)
//
#include <hip/hip_runtime.h>
#include <hip/hip_bf16.h>

typedef unsigned short u16;
typedef float floatx4 __attribute__((ext_vector_type(4)));
typedef __bf16 bf16x8 __attribute__((ext_vector_type(8)));
typedef _Float16 f16x8 __attribute__((ext_vector_type(8)));

#define NN 8192
#define DD 512
#define NPARTS 8
#define JCHUNK 1024   // NN / NPARTS

__device__ __forceinline__ u16 f2bf(float f) {
    __hip_bfloat16 h = __float2bfloat16(f);   // RNE
    return __builtin_bit_cast(u16, h);
}
__device__ __forceinline__ float bf2f(u16 u) {
    unsigned v = (unsigned)u << 16;
    return __builtin_bit_cast(float, v);
}
__device__ __forceinline__ u16 f2h(float f) {
    _Float16 h = (_Float16)f;                 // RNE
    return __builtin_bit_cast(u16, h);
}
__device__ __forceinline__ float h2f(u16 u) {
    _Float16 h = __builtin_bit_cast(_Float16, u);
    return (float)h;
}

// ---------------------------------------------------------------------------
// Projection GEMM with hi/lo bf16 split (fp32-accurate accumulator), output
// stored as SINGLE fp16. (unchanged from R3 — verified, absmax 0.0156)
// z=0: Q = x1@q (row-major fp16), z=1: K = x2@k, z=2: VT = (x1@v)^T
// ---------------------------------------------------------------------------
__global__ __launch_bounds__(256, 2)
void proj_kernel(const float* __restrict__ x1, const float* __restrict__ x2,
                 const float* __restrict__ qw, const float* __restrict__ kw,
                 const float* __restrict__ vw,
                 u16* __restrict__ Qf, u16* __restrict__ Kf, u16* __restrict__ VT)
{
    const int which = blockIdx.z;
    const float* A = (which == 1) ? x2 : x1;
    const float* W = (which == 0) ? qw : (which == 1 ? kw : vw);

    __shared__ u16 Ash[128 * 40], Asl[128 * 40];  // [m][k]
    __shared__ u16 Wsh[128 * 40], Wsl[128 * 40];  // [n][k] (W transposed)

    const int tid  = threadIdx.x;
    const int lane = tid & 63;
    const int wave = tid >> 6;
    const int l15  = lane & 15;
    const int quad = lane >> 4;
    const int wm   = (wave & 1) * 64;
    const int wn   = (wave >> 1) * 64;
    const int m0   = blockIdx.x * 128;
    const int n0   = blockIdx.y * 128;

    floatx4 acc[4][4] = {};

    for (int k0 = 0; k0 < DD; k0 += 32) {
        __syncthreads();
        {   // Stage A tile: 128 x 32 fp32 -> hi/lo bf16 [m][k]
            const int cg = (tid & 7) * 4;
            for (int i = 0; i < 4; i++) {
                const int row = (tid >> 3) + i * 32;
                float4 f = *(const float4*)&A[(size_t)(m0 + row) * DD + k0 + cg];
                u16 hx = f2bf(f.x), hy = f2bf(f.y), hz = f2bf(f.z), hw = f2bf(f.w);
                uint2 ph, pl;
                ph.x = ((unsigned)hy << 16) | hx;
                ph.y = ((unsigned)hw << 16) | hz;
                pl.x = ((unsigned)f2bf(f.y - bf2f(hy)) << 16) | f2bf(f.x - bf2f(hx));
                pl.y = ((unsigned)f2bf(f.w - bf2f(hw)) << 16) | f2bf(f.z - bf2f(hz));
                *(uint2*)&Ash[row * 40 + cg] = ph;
                *(uint2*)&Asl[row * 40 + cg] = pl;
            }
        }
        {   // Stage W tile: 32(k) x 128(n) -> hi/lo [n][k]
            const int kr = tid & 31;
            const int g  = tid >> 5;
            for (int i = 0; i < 4; i++) {
                const int n = (g + i * 8) * 4;
                float4 f = *(const float4*)&W[(size_t)(k0 + kr) * DD + n0 + n];
                float e[4] = {f.x, f.y, f.z, f.w};
                for (int j = 0; j < 4; j++) {
                    u16 h = f2bf(e[j]);
                    Wsh[(n + j) * 40 + kr] = h;
                    Wsl[(n + j) * 40 + kr] = f2bf(e[j] - bf2f(h));
                }
            }
        }
        __syncthreads();

        bf16x8 ah[4], al[4], bh[4], bl[4];
        for (int mi = 0; mi < 4; mi++) {
            ah[mi] = *(const bf16x8*)&Ash[(wm + mi * 16 + l15) * 40 + quad * 8];
            al[mi] = *(const bf16x8*)&Asl[(wm + mi * 16 + l15) * 40 + quad * 8];
        }
        for (int ni = 0; ni < 4; ni++) {
            bh[ni] = *(const bf16x8*)&Wsh[(wn + ni * 16 + l15) * 40 + quad * 8];
            bl[ni] = *(const bf16x8*)&Wsl[(wn + ni * 16 + l15) * 40 + quad * 8];
        }
        for (int mi = 0; mi < 4; mi++)
            for (int ni = 0; ni < 4; ni++) {
                acc[mi][ni] = __builtin_amdgcn_mfma_f32_16x16x32_bf16(ah[mi], bh[ni], acc[mi][ni], 0, 0, 0);
                acc[mi][ni] = __builtin_amdgcn_mfma_f32_16x16x32_bf16(ah[mi], bl[ni], acc[mi][ni], 0, 0, 0);
                acc[mi][ni] = __builtin_amdgcn_mfma_f32_16x16x32_bf16(al[mi], bh[ni], acc[mi][ni], 0, 0, 0);
            }
    }

    // Epilogue: C/D layout col = lane&15, row = quad*4 + reg; store fp16
    for (int mi = 0; mi < 4; mi++)
        for (int ni = 0; ni < 4; ni++)
            for (int r = 0; r < 4; r++) {
                const int row = m0 + wm + mi * 16 + quad * 4 + r;
                const int col = n0 + wn + ni * 16 + l15;
                const u16 hv = f2h(acc[mi][ni][r]);
                if (which == 0)      Qf[(size_t)row * DD + col] = hv;
                else if (which == 1) Kf[(size_t)row * DD + col] = hv;
                else                 VT[(size_t)col * NN + row] = hv;
            }
}

// ---------------------------------------------------------------------------
// Flash attention partials — BARRIER-FREE. Grid 1024 blocks (rb x part),
// 256 thr = 4 independent waves, 16 Q rows each. Q resident in registers
// (16 f16x8 = 64 VGPR); K and V^T B-fragments loaded directly from global
// (row-major layouts give the exact MFMA B layout; served by L1/L2 —
// XCD swizzle part = bid&7 keeps one part (2MB K + 2MB V) per XCD L2).
// Zero __syncthreads. LDS = per-wave P transpose only (same-wave lgkmcnt).
// ---------------------------------------------------------------------------
__global__ __launch_bounds__(256, 2)
void attn_kernel(const u16* __restrict__ Qf, const u16* __restrict__ Kf,
                 const u16* __restrict__ VT,
                 u16* __restrict__ Opart, float* __restrict__ Mp,
                 float* __restrict__ Lp)
{
    const int bid  = blockIdx.x;
    const int part = bid & 7;           // XCD-aligned: xcd = bid % 8 (heuristic)
    const int rb   = bid >> 3;
    const int tid  = threadIdx.x;
    const int lane = tid & 63;
    const int wave = tid >> 6;
    const int l15  = lane & 15;
    const int quad = lane >> 4;

    __shared__ u16 Ps[4][16 * 68];      // per-wave P [qrow][j], stride 68

    const int q0 = rb * 64 + wave * 16; // wave's Q rows

    // ---- Q resident: 16 A-fragments (full D=512) ----
    f16x8 qf[16];
    for (int kk = 0; kk < 16; kk++)
        qf[kk] = *(const f16x8*)&Qf[(size_t)(q0 + l15) * DD + kk * 32 + quad * 8];

    floatx4 o[32] = {};                 // O: 16 rows x 512 cols (C-layout)
    float m_run[4], l_run[4];
    for (int r = 0; r < 4; r++) { m_run[r] = -1e30f; l_run[r] = 0.f; }

    const int j_begin = part * JCHUNK;
    const int j_end   = j_begin + JCHUNK;

    for (int j0 = j_begin; j0 < j_end; j0 += 64) {
        // ---- S = Q K^T (B-frags straight from global; L1/L2-hot) ----
        floatx4 s[4] = {};
        for (int kk = 0; kk < 16; kk++)
            for (int nt = 0; nt < 4; nt++) {
                f16x8 b = *(const f16x8*)&Kf[(size_t)(j0 + nt * 16 + l15) * DD + kk * 32 + quad * 8];
                s[nt] = __builtin_amdgcn_mfma_f32_16x16x32_f16(qf[kk], b, s[nt], 0, 0, 0);
            }

        // ---- leaky_relu + online softmax ----
        for (int nt = 0; nt < 4; nt++)
            for (int r = 0; r < 4; r++) {
                float x = s[nt][r];
                s[nt][r] = x >= 0.f ? x : 0.01f * x;
            }
        float mt[4];
        for (int r = 0; r < 4; r++)
            mt[r] = fmaxf(fmaxf(s[0][r], s[1][r]), fmaxf(s[2][r], s[3][r]));
        for (int off = 1; off < 16; off <<= 1)
            for (int r = 0; r < 4; r++)
                mt[r] = fmaxf(mt[r], __shfl_xor(mt[r], off));

        float alpha[4];
        for (int r = 0; r < 4; r++) {
            const float mnew = fmaxf(m_run[r], mt[r]);
            alpha[r] = __expf(m_run[r] - mnew);
            m_run[r] = mnew;
        }
        float ls[4] = {0.f, 0.f, 0.f, 0.f};
        u16 pv[4][4];
        for (int nt = 0; nt < 4; nt++)
            for (int r = 0; r < 4; r++) {
                const float p = __expf(s[nt][r] - m_run[r]);
                ls[r] += p;
                pv[nt][r] = f2h(p);
            }
        for (int off = 1; off < 16; off <<= 1)
            for (int r = 0; r < 4; r++)
                ls[r] += __shfl_xor(ls[r], off);
        for (int r = 0; r < 4; r++)
            l_run[r] = l_run[r] * alpha[r] + ls[r];
        const bool need = (alpha[0] != 1.f) | (alpha[1] != 1.f) |
                          (alpha[2] != 1.f) | (alpha[3] != 1.f);
        if (__any(need))
            for (int i = 0; i < 32; i++)
                for (int r = 0; r < 4; r++)
                    o[i][r] *= alpha[r];

        // ---- P: C-layout -> A-layout via per-wave LDS (no barrier) ----
        for (int nt = 0; nt < 4; nt++)
            for (int r = 0; r < 4; r++)
                Ps[wave][(quad * 4 + r) * 68 + nt * 16 + l15] = pv[nt][r];
        asm volatile("s_waitcnt lgkmcnt(0)" ::: "memory");
        f16x8 pf[2];
        for (int ks = 0; ks < 2; ks++)
            pf[ks] = *(const f16x8*)&Ps[wave][l15 * 68 + ks * 32 + quad * 8];

        // ---- O += P @ V (V^T B-frags straight from global) ----
        for (int nt2 = 0; nt2 < 32; nt2++) {
            const u16* vrow = &VT[(size_t)(nt2 * 16 + l15) * NN + j0 + quad * 8];
            f16x8 b0 = *(const f16x8*)&vrow[0];
            f16x8 b1 = *(const f16x8*)&vrow[32];
            o[nt2] = __builtin_amdgcn_mfma_f32_16x16x32_f16(pf[0], b0, o[nt2], 0, 0, 0);
            o[nt2] = __builtin_amdgcn_mfma_f32_16x16x32_f16(pf[1], b1, o[nt2], 0, 0, 0);
        }
    }

    // ---- write partials (fp16 un-normalized O + fp32 m,l) ----
    for (int i = 0; i < 32; i++)
        for (int r = 0; r < 4; r++) {
            const int row = q0 + quad * 4 + r;
            const int col = i * 16 + l15;
            Opart[((size_t)part * NN + row) * DD + col] = f2h(o[i][r]);
        }
    if (l15 == 0)
        for (int r = 0; r < 4; r++) {
            const int row = q0 + quad * 4 + r;
            Mp[part * NN + row] = m_run[r];
            Lp[part * NN + row] = l_run[r];
        }
}

// ---------------------------------------------------------------------------
// Combine NPARTS j-partials: out = sum_p w_p O_p / sum_p w_p l_p
// ---------------------------------------------------------------------------
__global__ __launch_bounds__(256)
void combine_kernel(const u16* __restrict__ Opart, const float* __restrict__ Mp,
                    const float* __restrict__ Lp, float* __restrict__ out)
{
    const int row = blockIdx.x;
    const int tid = threadIdx.x;
    float m[NPARTS], l[NPARTS];
    float M = -1e30f;
    for (int p = 0; p < NPARTS; p++) {
        m[p] = Mp[p * NN + row];
        l[p] = Lp[p * NN + row];
        M = fmaxf(M, m[p]);
    }
    float w[NPARTS], L = 0.f;
    for (int p = 0; p < NPARTS; p++) { w[p] = __expf(m[p] - M); L += w[p] * l[p]; }
    const float inv = 1.f / L;
    for (int d = tid; d < DD; d += 256) {
        float acc = 0.f;
        for (int p = 0; p < NPARTS; p++)
            acc += w[p] * h2f(Opart[((size_t)p * NN + row) * DD + d]);
        out[(size_t)row * DD + d] = acc * inv;
    }
}

// ---------------------------------------------------------------------------
extern "C" void kernel_launch(void* const* d_in, const int* in_sizes, int n_in,
                              void* d_out, int out_size, void* d_ws, size_t ws_size,
                              hipStream_t stream)
{
    const float* x1 = (const float*)d_in[0];
    const float* x2 = (const float*)d_in[1];
    const float* qw = (const float*)d_in[2];
    const float* kw = (const float*)d_in[3];
    const float* vw = (const float*)d_in[4];
    float* out = (float*)d_out;

    // workspace: Qf|Kf|VT (8MB each fp16) | Opart 64MB fp16 | Mp | Lp
    u16* Qf = (u16*)d_ws;
    u16* Kf = Qf + (size_t)NN * DD;
    u16* VT = Kf + (size_t)NN * DD;
    u16* Opart = VT + (size_t)NN * DD;
    float* Mp = (float*)(Opart + (size_t)NPARTS * NN * DD);
    float* Lp = Mp + NPARTS * NN;

    proj_kernel<<<dim3(64, 4, 3), 256, 0, stream>>>(x1, x2, qw, kw, vw, Qf, Kf, VT);
    attn_kernel<<<dim3(128 * NPARTS), 256, 0, stream>>>(Qf, Kf, VT, Opart, Mp, Lp);
    combine_kernel<<<NN, 256, 0, stream>>>(Opart, Mp, Lp, out);
}

// Round 5
// 721.354 us; speedup vs baseline: 1.7033x; 1.7033x over previous
//
#include <hip/hip_runtime.h>
#include <hip/hip_bf16.h>

typedef unsigned short u16;
typedef unsigned int u32;
typedef float floatx4 __attribute__((ext_vector_type(4)));
typedef __bf16 bf16x8 __attribute__((ext_vector_type(8)));
typedef _Float16 f16x8 __attribute__((ext_vector_type(8)));

#define NN 8192
#define DD 512
#define NPARTS 8
#define JCHUNK 1024   // NN / NPARTS

__device__ __forceinline__ u16 f2bf(float f) {
    __hip_bfloat16 h = __float2bfloat16(f);   // RNE
    return __builtin_bit_cast(u16, h);
}
__device__ __forceinline__ float bf2f(u16 u) {
    unsigned v = (unsigned)u << 16;
    return __builtin_bit_cast(float, v);
}
__device__ __forceinline__ u16 f2h(float f) {
    _Float16 h = (_Float16)f;                 // RNE
    return __builtin_bit_cast(u16, h);
}
__device__ __forceinline__ float h2f(u16 u) {
    _Float16 h = __builtin_bit_cast(_Float16, u);
    return (float)h;
}

// async 16B-per-lane global->LDS DMA. LDS dest = base + lane*16 (wave-uniform
// base, contiguous); global src is per-lane (we use it to apply XOR swizzle).
__device__ __forceinline__ void async16(const u16* g, u16* l) {
    __builtin_amdgcn_global_load_lds(
        (const __attribute__((address_space(1))) u32*)g,
        (__attribute__((address_space(3))) u32*)l, 16, 0, 0);
}

// ---------------------------------------------------------------------------
// Projection GEMM with hi/lo bf16 split (fp32-accurate accumulator), output
// stored as SINGLE fp16. (unchanged — verified, absmax 0.0156)
// z=0: Q = x1@q (row-major fp16), z=1: K = x2@k, z=2: VT = (x1@v)^T
// ---------------------------------------------------------------------------
__global__ __launch_bounds__(256, 2)
void proj_kernel(const float* __restrict__ x1, const float* __restrict__ x2,
                 const float* __restrict__ qw, const float* __restrict__ kw,
                 const float* __restrict__ vw,
                 u16* __restrict__ Qf, u16* __restrict__ Kf, u16* __restrict__ VT)
{
    const int which = blockIdx.z;
    const float* A = (which == 1) ? x2 : x1;
    const float* W = (which == 0) ? qw : (which == 1 ? kw : vw);

    __shared__ u16 Ash[128 * 40], Asl[128 * 40];  // [m][k]
    __shared__ u16 Wsh[128 * 40], Wsl[128 * 40];  // [n][k] (W transposed)

    const int tid  = threadIdx.x;
    const int lane = tid & 63;
    const int wave = tid >> 6;
    const int l15  = lane & 15;
    const int quad = lane >> 4;
    const int wm   = (wave & 1) * 64;
    const int wn   = (wave >> 1) * 64;
    const int m0   = blockIdx.x * 128;
    const int n0   = blockIdx.y * 128;

    floatx4 acc[4][4] = {};

    for (int k0 = 0; k0 < DD; k0 += 32) {
        __syncthreads();
        {   // Stage A tile: 128 x 32 fp32 -> hi/lo bf16 [m][k]
            const int cg = (tid & 7) * 4;
            for (int i = 0; i < 4; i++) {
                const int row = (tid >> 3) + i * 32;
                float4 f = *(const float4*)&A[(size_t)(m0 + row) * DD + k0 + cg];
                u16 hx = f2bf(f.x), hy = f2bf(f.y), hz = f2bf(f.z), hw = f2bf(f.w);
                uint2 ph, pl;
                ph.x = ((unsigned)hy << 16) | hx;
                ph.y = ((unsigned)hw << 16) | hz;
                pl.x = ((unsigned)f2bf(f.y - bf2f(hy)) << 16) | f2bf(f.x - bf2f(hx));
                pl.y = ((unsigned)f2bf(f.w - bf2f(hw)) << 16) | f2bf(f.z - bf2f(hz));
                *(uint2*)&Ash[row * 40 + cg] = ph;
                *(uint2*)&Asl[row * 40 + cg] = pl;
            }
        }
        {   // Stage W tile: 32(k) x 128(n) -> hi/lo [n][k]
            const int kr = tid & 31;
            const int g  = tid >> 5;
            for (int i = 0; i < 4; i++) {
                const int n = (g + i * 8) * 4;
                float4 f = *(const float4*)&W[(size_t)(k0 + kr) * DD + n0 + n];
                float e[4] = {f.x, f.y, f.z, f.w};
                for (int j = 0; j < 4; j++) {
                    u16 h = f2bf(e[j]);
                    Wsh[(n + j) * 40 + kr] = h;
                    Wsl[(n + j) * 40 + kr] = f2bf(e[j] - bf2f(h));
                }
            }
        }
        __syncthreads();

        bf16x8 ah[4], al[4], bh[4], bl[4];
        for (int mi = 0; mi < 4; mi++) {
            ah[mi] = *(const bf16x8*)&Ash[(wm + mi * 16 + l15) * 40 + quad * 8];
            al[mi] = *(const bf16x8*)&Asl[(wm + mi * 16 + l15) * 40 + quad * 8];
        }
        for (int ni = 0; ni < 4; ni++) {
            bh[ni] = *(const bf16x8*)&Wsh[(wn + ni * 16 + l15) * 40 + quad * 8];
            bl[ni] = *(const bf16x8*)&Wsl[(wn + ni * 16 + l15) * 40 + quad * 8];
        }
        for (int mi = 0; mi < 4; mi++)
            for (int ni = 0; ni < 4; ni++) {
                acc[mi][ni] = __builtin_amdgcn_mfma_f32_16x16x32_bf16(ah[mi], bh[ni], acc[mi][ni], 0, 0, 0);
                acc[mi][ni] = __builtin_amdgcn_mfma_f32_16x16x32_bf16(ah[mi], bl[ni], acc[mi][ni], 0, 0, 0);
                acc[mi][ni] = __builtin_amdgcn_mfma_f32_16x16x32_bf16(al[mi], bh[ni], acc[mi][ni], 0, 0, 0);
            }
    }

    // Epilogue: C/D layout col = lane&15, row = quad*4 + reg; store fp16
    for (int mi = 0; mi < 4; mi++)
        for (int ni = 0; ni < 4; ni++)
            for (int r = 0; r < 4; r++) {
                const int row = m0 + wm + mi * 16 + quad * 4 + r;
                const int col = n0 + wn + ni * 16 + l15;
                const u16 hv = f2h(acc[mi][ni][r]);
                if (which == 0)      Qf[(size_t)row * DD + col] = hv;
                else if (which == 1) Kf[(size_t)row * DD + col] = hv;
                else                 VT[(size_t)col * NN + row] = hv;
            }
}

// ---------------------------------------------------------------------------
// Flash attention partials — async-DMA pipelined. Grid 1024 blocks, 256 thr
// (4 waves x 16 Q rows). Per 64-j tile: 4 phases on a 2x32KB LDS ring:
//   p0: QK on K[d 0..255]   (issues K-hi DMA)
//   p1: QK on K[d 256..511] + softmax/P  (issues V-lo DMA)
//   p2: PV on V[d 0..255]   (issues V-hi DMA)
//   p3: PV on V[d 256..511] (issues next tile's K-lo DMA)
// DMA issued at phase top lands during the phase's ~32 MFMAs; the phase-end
// __syncthreads vmcnt drain is then cheap. XOR swizzle (chunk ^= row&7) on
// DMA source + LDS reads keeps ds_read_b128 2-way (free).
// ---------------------------------------------------------------------------
__global__ __launch_bounds__(256, 2)
void attn_kernel(const u16* __restrict__ Qf, const u16* __restrict__ Kf,
                 const u16* __restrict__ VT,
                 u16* __restrict__ Opart, float* __restrict__ Mp,
                 float* __restrict__ Lp)
{
    const int bid  = blockIdx.x;
    const int part = bid & 7;           // XCD-pinned j-part
    const int rb   = bid >> 3;
    const int tid  = threadIdx.x;
    const int lane = tid & 63;
    const int wave = tid >> 6;
    const int l15  = lane & 15;
    const int quad = lane >> 4;

    __shared__ u16 KV[2][16384];        // ring: K-half = 64r x 256c, V-half = 256r x 64c
    __shared__ u16 Ps[4][16 * 68];      // per-wave P transpose

    const int q0 = rb * 64 + wave * 16;

    // Q resident: 16 A-fragments (full D=512)
    f16x8 qf[16];
    for (int kk = 0; kk < 16; kk++)
        qf[kk] = *(const f16x8*)&Qf[(size_t)(q0 + l15) * DD + kk * 32 + quad * 8];

    floatx4 o[32] = {};
    float m_run[4], l_run[4];
    for (int r = 0; r < 4; r++) { m_run[r] = -1e30f; l_run[r] = 0.f; }

    const int j_begin = part * JCHUNK;
    const int j_end   = j_begin + JCHUNK;

    // --- staging (async DMA, swizzled source) ---
    const int krs  = lane >> 5;         // K: row-sub 0..1
    const int kpos = lane & 31;         // K: chunk position in row
    const int vrs  = lane >> 3;         // V: row-sub 0..7
    const int vch  = (lane & 7) ^ vrs;  // V: swizzled source chunk

    auto stageK = [&](int h, int j0, int r) {
        for (int c = 0; c < 8; c++) {
            const int jj  = wave * 16 + c * 2;              // even row pair
            const int row = jj + krs;
            const int sch = kpos ^ (row & 7);
            async16(&Kf[(size_t)(j0 + row) * DD + h * 256 + sch * 8],
                    &KV[r][jj * 256]);
        }
    };
    auto stageV = [&](int h, int j0, int r) {
        for (int c = 0; c < 8; c++) {
            const int dl = wave * 64 + c * 8;               // local d base
            async16(&VT[(size_t)(h * 256 + dl + vrs) * NN + j0 + vch * 8],
                    &KV[r][dl * 64]);
        }
    };

    // --- compute helpers ---
    auto qkHalf = [&](int r, int kb, floatx4* s) {
        for (int k8 = 0; k8 < 8; k8++)
            for (int nt = 0; nt < 4; nt++) {
                const int row = nt * 16 + l15;
                const int ch  = (k8 * 4 + quad) ^ (l15 & 7);
                f16x8 b = *(const f16x8*)&KV[r][row * 256 + ch * 8];
                s[nt] = __builtin_amdgcn_mfma_f32_16x16x32_f16(qf[kb + k8], b, s[nt], 0, 0, 0);
            }
    };
    auto pvHalf = [&](int r, int ob, f16x8* pf) {
        for (int t = 0; t < 16; t++) {
            const int row = t * 16 + l15;
            const int c0  = quad ^ (l15 & 7);
            const int c1  = (4 + quad) ^ (l15 & 7);
            f16x8 b0 = *(const f16x8*)&KV[r][row * 64 + c0 * 8];
            f16x8 b1 = *(const f16x8*)&KV[r][row * 64 + c1 * 8];
            o[ob + t] = __builtin_amdgcn_mfma_f32_16x16x32_f16(pf[0], b0, o[ob + t], 0, 0, 0);
            o[ob + t] = __builtin_amdgcn_mfma_f32_16x16x32_f16(pf[1], b1, o[ob + t], 0, 0, 0);
        }
    };

    // preamble: K-lo of first tile into region 0
    stageK(0, j_begin, 0);
    __syncthreads();

    for (int j0 = j_begin; j0 < j_end; j0 += 64) {
        floatx4 s[4] = {};

        // ---- p0: QK on K-lo (r0); prefetch K-hi -> r1 ----
        stageK(1, j0, 1);
        qkHalf(0, 0, s);
        __syncthreads();

        // ---- p1: QK on K-hi (r1); prefetch V-lo -> r0; softmax ----
        stageV(0, j0, 0);
        qkHalf(1, 8, s);

        for (int nt = 0; nt < 4; nt++)
            for (int r = 0; r < 4; r++) {
                float x = s[nt][r];
                s[nt][r] = x >= 0.f ? x : 0.01f * x;
            }
        float mt[4];
        for (int r = 0; r < 4; r++)
            mt[r] = fmaxf(fmaxf(s[0][r], s[1][r]), fmaxf(s[2][r], s[3][r]));
        for (int off = 1; off < 16; off <<= 1)
            for (int r = 0; r < 4; r++)
                mt[r] = fmaxf(mt[r], __shfl_xor(mt[r], off));

        float alpha[4];
        for (int r = 0; r < 4; r++) {
            const float mnew = fmaxf(m_run[r], mt[r]);
            alpha[r] = __expf(m_run[r] - mnew);
            m_run[r] = mnew;
        }
        float ls[4] = {0.f, 0.f, 0.f, 0.f};
        u16 pv[4][4];
        for (int nt = 0; nt < 4; nt++)
            for (int r = 0; r < 4; r++) {
                const float p = __expf(s[nt][r] - m_run[r]);
                ls[r] += p;
                pv[nt][r] = f2h(p);
            }
        for (int off = 1; off < 16; off <<= 1)
            for (int r = 0; r < 4; r++)
                ls[r] += __shfl_xor(ls[r], off);
        for (int r = 0; r < 4; r++)
            l_run[r] = l_run[r] * alpha[r] + ls[r];
        const bool need = (alpha[0] != 1.f) | (alpha[1] != 1.f) |
                          (alpha[2] != 1.f) | (alpha[3] != 1.f);
        if (__any(need))
            for (int i = 0; i < 32; i++)
                for (int r = 0; r < 4; r++)
                    o[i][r] *= alpha[r];

        // P: C-layout -> A-layout via per-wave LDS (no barrier)
        for (int nt = 0; nt < 4; nt++)
            for (int r = 0; r < 4; r++)
                Ps[wave][(quad * 4 + r) * 68 + nt * 16 + l15] = pv[nt][r];
        asm volatile("s_waitcnt lgkmcnt(0)" ::: "memory");
        f16x8 pf[2];
        for (int ks = 0; ks < 2; ks++)
            pf[ks] = *(const f16x8*)&Ps[wave][l15 * 68 + ks * 32 + quad * 8];
        __syncthreads();

        // ---- p2: PV on V-lo (r0); prefetch V-hi -> r1 ----
        stageV(1, j0, 1);
        pvHalf(0, 0, pf);
        __syncthreads();

        // ---- p3: PV on V-hi (r1); prefetch next K-lo -> r0 ----
        if (j0 + 64 < j_end) stageK(0, j0 + 64, 0);
        pvHalf(1, 16, pf);
        __syncthreads();
    }

    // ---- write partials (fp16 un-normalized O + fp32 m,l) ----
    for (int i = 0; i < 32; i++)
        for (int r = 0; r < 4; r++) {
            const int row = q0 + quad * 4 + r;
            const int col = i * 16 + l15;
            Opart[((size_t)part * NN + row) * DD + col] = f2h(o[i][r]);
        }
    if (l15 == 0)
        for (int r = 0; r < 4; r++) {
            const int row = q0 + quad * 4 + r;
            Mp[part * NN + row] = m_run[r];
            Lp[part * NN + row] = l_run[r];
        }
}

// ---------------------------------------------------------------------------
// Combine NPARTS j-partials: out = sum_p w_p O_p / sum_p w_p l_p
// ---------------------------------------------------------------------------
__global__ __launch_bounds__(256)
void combine_kernel(const u16* __restrict__ Opart, const float* __restrict__ Mp,
                    const float* __restrict__ Lp, float* __restrict__ out)
{
    const int row = blockIdx.x;
    const int tid = threadIdx.x;
    float m[NPARTS], l[NPARTS];
    float M = -1e30f;
    for (int p = 0; p < NPARTS; p++) {
        m[p] = Mp[p * NN + row];
        l[p] = Lp[p * NN + row];
        M = fmaxf(M, m[p]);
    }
    float w[NPARTS], L = 0.f;
    for (int p = 0; p < NPARTS; p++) { w[p] = __expf(m[p] - M); L += w[p] * l[p]; }
    const float inv = 1.f / L;
    for (int d = tid; d < DD; d += 256) {
        float acc = 0.f;
        for (int p = 0; p < NPARTS; p++)
            acc += w[p] * h2f(Opart[((size_t)p * NN + row) * DD + d]);
        out[(size_t)row * DD + d] = acc * inv;
    }
}

// ---------------------------------------------------------------------------
extern "C" void kernel_launch(void* const* d_in, const int* in_sizes, int n_in,
                              void* d_out, int out_size, void* d_ws, size_t ws_size,
                              hipStream_t stream)
{
    const float* x1 = (const float*)d_in[0];
    const float* x2 = (const float*)d_in[1];
    const float* qw = (const float*)d_in[2];
    const float* kw = (const float*)d_in[3];
    const float* vw = (const float*)d_in[4];
    float* out = (float*)d_out;

    // workspace: Qf|Kf|VT (8MB each fp16) | Opart 64MB fp16 | Mp | Lp
    u16* Qf = (u16*)d_ws;
    u16* Kf = Qf + (size_t)NN * DD;
    u16* VT = Kf + (size_t)NN * DD;
    u16* Opart = VT + (size_t)NN * DD;
    float* Mp = (float*)(Opart + (size_t)NPARTS * NN * DD);
    float* Lp = Mp + NPARTS * NN;

    proj_kernel<<<dim3(64, 4, 3), 256, 0, stream>>>(x1, x2, qw, kw, vw, Qf, Kf, VT);
    attn_kernel<<<dim3(128 * NPARTS), 256, 0, stream>>>(Qf, Kf, VT, Opart, Mp, Lp);
    combine_kernel<<<NN, 256, 0, stream>>>(Opart, Mp, Lp, out);
}

// Round 6
// 634.323 us; speedup vs baseline: 1.9370x; 1.1372x over previous
//
#include <hip/hip_runtime.h>
#include <hip/hip_bf16.h>

typedef unsigned short u16;
typedef unsigned int u32;
typedef float floatx4 __attribute__((ext_vector_type(4)));
typedef __bf16 bf16x8 __attribute__((ext_vector_type(8)));
typedef _Float16 f16x8 __attribute__((ext_vector_type(8)));

#define NN 8192
#define DD 512
#define NPARTS 8
#define JCHUNK 1024       // NN / NPARTS
#define RB_PER_PART 128   // row-blocks (64 Q rows each) per part

__device__ __forceinline__ u16 f2bf(float f) {
    __hip_bfloat16 h = __float2bfloat16(f);   // RNE
    return __builtin_bit_cast(u16, h);
}
__device__ __forceinline__ float bf2f(u16 u) {
    unsigned v = (unsigned)u << 16;
    return __builtin_bit_cast(float, v);
}
__device__ __forceinline__ u16 f2h(float f) {
    _Float16 h = (_Float16)f;                 // RNE
    return __builtin_bit_cast(u16, h);
}
__device__ __forceinline__ float h2f(u16 u) {
    _Float16 h = __builtin_bit_cast(_Float16, u);
    return (float)h;
}

// async 16B-per-lane global->LDS DMA (wave-uniform LDS base + lane*16).
__device__ __forceinline__ void async16(const u16* g, u16* l) {
    __builtin_amdgcn_global_load_lds(
        (const __attribute__((address_space(1))) u32*)g,
        (__attribute__((address_space(3))) u32*)l, 16, 0, 0);
}

// ---------------------------------------------------------------------------
// Projection GEMM with hi/lo bf16 split (fp32-accurate accumulator), output
// stored as SINGLE fp16. (unchanged — verified, absmax 0.0156)
// z=0: Q = x1@q (row-major fp16), z=1: K = x2@k, z=2: VT = (x1@v)^T
// ---------------------------------------------------------------------------
__global__ __launch_bounds__(256, 2)
void proj_kernel(const float* __restrict__ x1, const float* __restrict__ x2,
                 const float* __restrict__ qw, const float* __restrict__ kw,
                 const float* __restrict__ vw,
                 u16* __restrict__ Qf, u16* __restrict__ Kf, u16* __restrict__ VT)
{
    const int which = blockIdx.z;
    const float* A = (which == 1) ? x2 : x1;
    const float* W = (which == 0) ? qw : (which == 1 ? kw : vw);

    __shared__ u16 Ash[128 * 40], Asl[128 * 40];  // [m][k]
    __shared__ u16 Wsh[128 * 40], Wsl[128 * 40];  // [n][k] (W transposed)

    const int tid  = threadIdx.x;
    const int lane = tid & 63;
    const int wave = tid >> 6;
    const int l15  = lane & 15;
    const int quad = lane >> 4;
    const int wm   = (wave & 1) * 64;
    const int wn   = (wave >> 1) * 64;
    const int m0   = blockIdx.x * 128;
    const int n0   = blockIdx.y * 128;

    floatx4 acc[4][4] = {};

    for (int k0 = 0; k0 < DD; k0 += 32) {
        __syncthreads();
        {   // Stage A tile: 128 x 32 fp32 -> hi/lo bf16 [m][k]
            const int cg = (tid & 7) * 4;
            for (int i = 0; i < 4; i++) {
                const int row = (tid >> 3) + i * 32;
                float4 f = *(const float4*)&A[(size_t)(m0 + row) * DD + k0 + cg];
                u16 hx = f2bf(f.x), hy = f2bf(f.y), hz = f2bf(f.z), hw = f2bf(f.w);
                uint2 ph, pl;
                ph.x = ((unsigned)hy << 16) | hx;
                ph.y = ((unsigned)hw << 16) | hz;
                pl.x = ((unsigned)f2bf(f.y - bf2f(hy)) << 16) | f2bf(f.x - bf2f(hx));
                pl.y = ((unsigned)f2bf(f.w - bf2f(hw)) << 16) | f2bf(f.z - bf2f(hz));
                *(uint2*)&Ash[row * 40 + cg] = ph;
                *(uint2*)&Asl[row * 40 + cg] = pl;
            }
        }
        {   // Stage W tile: 32(k) x 128(n) -> hi/lo [n][k]
            const int kr = tid & 31;
            const int g  = tid >> 5;
            for (int i = 0; i < 4; i++) {
                const int n = (g + i * 8) * 4;
                float4 f = *(const float4*)&W[(size_t)(k0 + kr) * DD + n0 + n];
                float e[4] = {f.x, f.y, f.z, f.w};
                for (int j = 0; j < 4; j++) {
                    u16 h = f2bf(e[j]);
                    Wsh[(n + j) * 40 + kr] = h;
                    Wsl[(n + j) * 40 + kr] = f2bf(e[j] - bf2f(h));
                }
            }
        }
        __syncthreads();

        bf16x8 ah[4], al[4], bh[4], bl[4];
        for (int mi = 0; mi < 4; mi++) {
            ah[mi] = *(const bf16x8*)&Ash[(wm + mi * 16 + l15) * 40 + quad * 8];
            al[mi] = *(const bf16x8*)&Asl[(wm + mi * 16 + l15) * 40 + quad * 8];
        }
        for (int ni = 0; ni < 4; ni++) {
            bh[ni] = *(const bf16x8*)&Wsh[(wn + ni * 16 + l15) * 40 + quad * 8];
            bl[ni] = *(const bf16x8*)&Wsl[(wn + ni * 16 + l15) * 40 + quad * 8];
        }
        for (int mi = 0; mi < 4; mi++)
            for (int ni = 0; ni < 4; ni++) {
                acc[mi][ni] = __builtin_amdgcn_mfma_f32_16x16x32_bf16(ah[mi], bh[ni], acc[mi][ni], 0, 0, 0);
                acc[mi][ni] = __builtin_amdgcn_mfma_f32_16x16x32_bf16(ah[mi], bl[ni], acc[mi][ni], 0, 0, 0);
                acc[mi][ni] = __builtin_amdgcn_mfma_f32_16x16x32_bf16(al[mi], bh[ni], acc[mi][ni], 0, 0, 0);
            }
    }

    // Epilogue: C/D layout col = lane&15, row = quad*4 + reg; store fp16
    for (int mi = 0; mi < 4; mi++)
        for (int ni = 0; ni < 4; ni++)
            for (int r = 0; r < 4; r++) {
                const int row = m0 + wm + mi * 16 + quad * 4 + r;
                const int col = n0 + wn + ni * 16 + l15;
                const u16 hv = f2h(acc[mi][ni][r]);
                if (which == 0)      Qf[(size_t)row * DD + col] = hv;
                else if (which == 1) Kf[(size_t)row * DD + col] = hv;
                else                 VT[(size_t)col * NN + row] = hv;
            }
}

// ---------------------------------------------------------------------------
// Flash attention partials — async-DMA pipelined + XCD-pinned work claiming.
// Each block reads its XCD id (HW_REG_XCC_ID, measured-real on MI355X) and
// atomically claims (part = my_xcd, rb = queue index) so each XCD's L2 only
// ever serves ONE 1MB K-part + 1MB V-part -> K/V restaging hits L2.
// Pigeonhole guarantees exact 1:1 coverage of all 1024 (part, rb) items.
// Pipeline per 64-j tile: 4 phases on a 2x32KB LDS ring (DMA 1 phase ahead).
// ---------------------------------------------------------------------------
__global__ __launch_bounds__(256, 2)
void attn_kernel(const u16* __restrict__ Qf, const u16* __restrict__ Kf,
                 const u16* __restrict__ VT,
                 u16* __restrict__ Opart, float* __restrict__ Mp,
                 float* __restrict__ Lp, int* __restrict__ cnt)
{
    const int tid  = threadIdx.x;
    const int lane = tid & 63;
    const int wave = tid >> 6;
    const int l15  = lane & 15;
    const int quad = lane >> 4;

    __shared__ u16 KV[2][16384];        // ring: K-half = 64r x 256c, V-half = 256r x 64c
    __shared__ u16 Ps[4][16 * 68];      // per-wave P transpose
    __shared__ int sPart, sRb;

    // ---- claim work item pinned to this block's physical XCD ----
    if (tid == 0) {
        u32 xcd;
        asm volatile("s_getreg_b32 %0, hwreg(HW_REG_XCC_ID)" : "=s"(xcd));
        xcd &= 7;
        int part = -1, rb = 0;
        for (int t = 0; t < 8; t++) {
            const int p = (xcd + t) & 7;
            const int idx = atomicAdd(&cnt[p], 1);
            if (idx < RB_PER_PART) { part = p; rb = idx; break; }
        }
        sPart = part; sRb = rb;
    }
    __syncthreads();
    const int part = sPart;
    const int rb   = sRb;
    if (part < 0) return;               // unreachable (pigeonhole)

    const int q0 = rb * 64 + wave * 16;

    // Q resident: 16 A-fragments (full D=512)
    f16x8 qf[16];
    for (int kk = 0; kk < 16; kk++)
        qf[kk] = *(const f16x8*)&Qf[(size_t)(q0 + l15) * DD + kk * 32 + quad * 8];

    floatx4 o[32] = {};
    float m_run[4], l_run[4];
    for (int r = 0; r < 4; r++) { m_run[r] = -1e30f; l_run[r] = 0.f; }

    const int j_begin = part * JCHUNK;
    const int j_end   = j_begin + JCHUNK;

    // --- staging (async DMA, swizzled source) ---
    const int krs  = lane >> 5;         // K: row-sub 0..1
    const int kpos = lane & 31;         // K: chunk position in row
    const int vrs  = lane >> 3;         // V: row-sub 0..7
    const int vch  = (lane & 7) ^ vrs;  // V: swizzled source chunk

    auto stageK = [&](int h, int j0, int r) {
        for (int c = 0; c < 8; c++) {
            const int jj  = wave * 16 + c * 2;              // even row pair
            const int row = jj + krs;
            const int sch = kpos ^ (row & 7);
            async16(&Kf[(size_t)(j0 + row) * DD + h * 256 + sch * 8],
                    &KV[r][jj * 256]);
        }
    };
    auto stageV = [&](int h, int j0, int r) {
        for (int c = 0; c < 8; c++) {
            const int dl = wave * 64 + c * 8;               // local d base
            async16(&VT[(size_t)(h * 256 + dl + vrs) * NN + j0 + vch * 8],
                    &KV[r][dl * 64]);
        }
    };

    // --- compute helpers ---
    auto qkHalf = [&](int r, int kb, floatx4* s) {
        for (int k8 = 0; k8 < 8; k8++)
            for (int nt = 0; nt < 4; nt++) {
                const int row = nt * 16 + l15;
                const int ch  = (k8 * 4 + quad) ^ (l15 & 7);
                f16x8 b = *(const f16x8*)&KV[r][row * 256 + ch * 8];
                s[nt] = __builtin_amdgcn_mfma_f32_16x16x32_f16(qf[kb + k8], b, s[nt], 0, 0, 0);
            }
    };
    auto pvHalf = [&](int r, int ob, f16x8* pf) {
        for (int t = 0; t < 16; t++) {
            const int row = t * 16 + l15;
            const int c0  = quad ^ (l15 & 7);
            const int c1  = (4 + quad) ^ (l15 & 7);
            f16x8 b0 = *(const f16x8*)&KV[r][row * 64 + c0 * 8];
            f16x8 b1 = *(const f16x8*)&KV[r][row * 64 + c1 * 8];
            o[ob + t] = __builtin_amdgcn_mfma_f32_16x16x32_f16(pf[0], b0, o[ob + t], 0, 0, 0);
            o[ob + t] = __builtin_amdgcn_mfma_f32_16x16x32_f16(pf[1], b1, o[ob + t], 0, 0, 0);
        }
    };

    // preamble: K-lo of first tile into region 0
    stageK(0, j_begin, 0);
    __syncthreads();

    for (int j0 = j_begin; j0 < j_end; j0 += 64) {
        floatx4 s[4] = {};

        // ---- p0: QK on K-lo (r0); prefetch K-hi -> r1 ----
        stageK(1, j0, 1);
        qkHalf(0, 0, s);
        __syncthreads();

        // ---- p1: QK on K-hi (r1); prefetch V-lo -> r0; softmax ----
        stageV(0, j0, 0);
        qkHalf(1, 8, s);

        for (int nt = 0; nt < 4; nt++)
            for (int r = 0; r < 4; r++) {
                float x = s[nt][r];
                s[nt][r] = x >= 0.f ? x : 0.01f * x;
            }
        float mt[4];
        for (int r = 0; r < 4; r++)
            mt[r] = fmaxf(fmaxf(s[0][r], s[1][r]), fmaxf(s[2][r], s[3][r]));
        for (int off = 1; off < 16; off <<= 1)
            for (int r = 0; r < 4; r++)
                mt[r] = fmaxf(mt[r], __shfl_xor(mt[r], off));

        float alpha[4];
        for (int r = 0; r < 4; r++) {
            const float mnew = fmaxf(m_run[r], mt[r]);
            alpha[r] = __expf(m_run[r] - mnew);
            m_run[r] = mnew;
        }
        float ls[4] = {0.f, 0.f, 0.f, 0.f};
        u16 pv[4][4];
        for (int nt = 0; nt < 4; nt++)
            for (int r = 0; r < 4; r++) {
                const float p = __expf(s[nt][r] - m_run[r]);
                ls[r] += p;
                pv[nt][r] = f2h(p);
            }
        for (int off = 1; off < 16; off <<= 1)
            for (int r = 0; r < 4; r++)
                ls[r] += __shfl_xor(ls[r], off);
        for (int r = 0; r < 4; r++)
            l_run[r] = l_run[r] * alpha[r] + ls[r];
        const bool need = (alpha[0] != 1.f) | (alpha[1] != 1.f) |
                          (alpha[2] != 1.f) | (alpha[3] != 1.f);
        if (__any(need))
            for (int i = 0; i < 32; i++)
                for (int r = 0; r < 4; r++)
                    o[i][r] *= alpha[r];

        // P: C-layout -> A-layout via per-wave LDS (no barrier)
        for (int nt = 0; nt < 4; nt++)
            for (int r = 0; r < 4; r++)
                Ps[wave][(quad * 4 + r) * 68 + nt * 16 + l15] = pv[nt][r];
        asm volatile("s_waitcnt lgkmcnt(0)" ::: "memory");
        f16x8 pf[2];
        for (int ks = 0; ks < 2; ks++)
            pf[ks] = *(const f16x8*)&Ps[wave][l15 * 68 + ks * 32 + quad * 8];
        __syncthreads();

        // ---- p2: PV on V-lo (r0); prefetch V-hi -> r1 ----
        stageV(1, j0, 1);
        pvHalf(0, 0, pf);
        __syncthreads();

        // ---- p3: PV on V-hi (r1); prefetch next K-lo -> r0 ----
        if (j0 + 64 < j_end) stageK(0, j0 + 64, 0);
        pvHalf(1, 16, pf);
        __syncthreads();
    }

    // ---- write partials (fp16 un-normalized O + fp32 m,l) ----
    for (int i = 0; i < 32; i++)
        for (int r = 0; r < 4; r++) {
            const int row = q0 + quad * 4 + r;
            const int col = i * 16 + l15;
            Opart[((size_t)part * NN + row) * DD + col] = f2h(o[i][r]);
        }
    if (l15 == 0)
        for (int r = 0; r < 4; r++) {
            const int row = q0 + quad * 4 + r;
            Mp[part * NN + row] = m_run[r];
            Lp[part * NN + row] = l_run[r];
        }
}

// ---------------------------------------------------------------------------
// Combine NPARTS j-partials: out = sum_p w_p O_p / sum_p w_p l_p
// ---------------------------------------------------------------------------
__global__ __launch_bounds__(256)
void combine_kernel(const u16* __restrict__ Opart, const float* __restrict__ Mp,
                    const float* __restrict__ Lp, float* __restrict__ out)
{
    const int row = blockIdx.x;
    const int tid = threadIdx.x;
    float m[NPARTS], l[NPARTS];
    float M = -1e30f;
    for (int p = 0; p < NPARTS; p++) {
        m[p] = Mp[p * NN + row];
        l[p] = Lp[p * NN + row];
        M = fmaxf(M, m[p]);
    }
    float w[NPARTS], L = 0.f;
    for (int p = 0; p < NPARTS; p++) { w[p] = __expf(m[p] - M); L += w[p] * l[p]; }
    const float inv = 1.f / L;
    for (int d = tid; d < DD; d += 256) {
        float acc = 0.f;
        for (int p = 0; p < NPARTS; p++)
            acc += w[p] * h2f(Opart[((size_t)p * NN + row) * DD + d]);
        out[(size_t)row * DD + d] = acc * inv;
    }
}

// ---------------------------------------------------------------------------
extern "C" void kernel_launch(void* const* d_in, const int* in_sizes, int n_in,
                              void* d_out, int out_size, void* d_ws, size_t ws_size,
                              hipStream_t stream)
{
    const float* x1 = (const float*)d_in[0];
    const float* x2 = (const float*)d_in[1];
    const float* qw = (const float*)d_in[2];
    const float* kw = (const float*)d_in[3];
    const float* vw = (const float*)d_in[4];
    float* out = (float*)d_out;

    // workspace: Qf|Kf|VT (8MB each fp16) | Opart 64MB fp16 | Mp | Lp | cnt[8]
    u16* Qf = (u16*)d_ws;
    u16* Kf = Qf + (size_t)NN * DD;
    u16* VT = Kf + (size_t)NN * DD;
    u16* Opart = VT + (size_t)NN * DD;
    float* Mp = (float*)(Opart + (size_t)NPARTS * NN * DD);
    float* Lp = Mp + NPARTS * NN;
    int* cnt = (int*)(Lp + NPARTS * NN);

    hipMemsetAsync(cnt, 0, NPARTS * sizeof(int), stream);
    proj_kernel<<<dim3(64, 4, 3), 256, 0, stream>>>(x1, x2, qw, kw, vw, Qf, Kf, VT);
    attn_kernel<<<dim3(RB_PER_PART * NPARTS), 256, 0, stream>>>(Qf, Kf, VT, Opart, Mp, Lp, cnt);
    combine_kernel<<<NN, 256, 0, stream>>>(Opart, Mp, Lp, out);
}

// Round 7
// 544.803 us; speedup vs baseline: 2.2552x; 1.1643x over previous
//
#include <hip/hip_runtime.h>
#include <hip/hip_bf16.h>

typedef unsigned short u16;
typedef unsigned int u32;
typedef float floatx4 __attribute__((ext_vector_type(4)));
typedef _Float16 f16x8 __attribute__((ext_vector_type(8)));

#define NN 8192
#define DD 512
#define NPARTS 8
#define JCHUNK 1024       // NN / NPARTS
#define RB_PER_PART 128   // row-blocks (64 Q rows each) per part

__device__ __forceinline__ u16 f2h(float f) {
    _Float16 h = (_Float16)f;                 // RNE
    return __builtin_bit_cast(u16, h);
}
__device__ __forceinline__ float h2f(u16 u) {
    _Float16 h = __builtin_bit_cast(_Float16, u);
    return (float)h;
}

// async 16B-per-lane global->LDS DMA (wave-uniform LDS base + lane*16).
__device__ __forceinline__ void async16(const u16* g, u16* l) {
    __builtin_amdgcn_global_load_lds(
        (const __attribute__((address_space(1))) u32*)g,
        (__attribute__((address_space(3))) u32*)l, 16, 0, 0);
}

// Pipeline barrier: wait only the 1-phase-old DMA group (4 instrs/wave),
// leave the newest 4 in flight. NOT __syncthreads (which drains vmcnt(0)).
#define PIPE_BAR() asm volatile("s_waitcnt vmcnt(4)\n\ts_barrier" ::: "memory")

// ---------------------------------------------------------------------------
// Projection GEMM, fp16 single-term (fp32 accumulate). Input fp16 rounding
// adds ~1.6e-4 logit sigma vs 2.6e-3 already present from Q/K fp16 storage.
// z=0: Q = x1@q (row-major fp16), z=1: K = x2@k, z=2: VT = (x1@v)^T
// ---------------------------------------------------------------------------
__global__ __launch_bounds__(256, 2)
void proj_kernel(const float* __restrict__ x1, const float* __restrict__ x2,
                 const float* __restrict__ qw, const float* __restrict__ kw,
                 const float* __restrict__ vw,
                 u16* __restrict__ Qf, u16* __restrict__ Kf, u16* __restrict__ VT)
{
    const int which = blockIdx.z;
    const float* A = (which == 1) ? x2 : x1;
    const float* W = (which == 0) ? qw : (which == 1 ? kw : vw);

    __shared__ u16 Ash[128 * 40];   // [m][k]
    __shared__ u16 Wsh[128 * 40];   // [n][k] (W transposed)

    const int tid  = threadIdx.x;
    const int lane = tid & 63;
    const int wave = tid >> 6;
    const int l15  = lane & 15;
    const int quad = lane >> 4;
    const int wm   = (wave & 1) * 64;
    const int wn   = (wave >> 1) * 64;
    const int m0   = blockIdx.x * 128;
    const int n0   = blockIdx.y * 128;

    floatx4 acc[4][4] = {};

    for (int k0 = 0; k0 < DD; k0 += 32) {
        __syncthreads();
        {   // Stage A tile: 128 x 32 fp32 -> fp16 [m][k]
            const int cg = (tid & 7) * 4;
            for (int i = 0; i < 4; i++) {
                const int row = (tid >> 3) + i * 32;
                float4 f = *(const float4*)&A[(size_t)(m0 + row) * DD + k0 + cg];
                uint2 p;
                p.x = ((unsigned)f2h(f.y) << 16) | f2h(f.x);
                p.y = ((unsigned)f2h(f.w) << 16) | f2h(f.z);
                *(uint2*)&Ash[row * 40 + cg] = p;
            }
        }
        {   // Stage W tile: 32(k) x 128(n) -> fp16 [n][k]
            const int kr = tid & 31;
            const int g  = tid >> 5;
            for (int i = 0; i < 4; i++) {
                const int n = (g + i * 8) * 4;
                float4 f = *(const float4*)&W[(size_t)(k0 + kr) * DD + n0 + n];
                Wsh[(n + 0) * 40 + kr] = f2h(f.x);
                Wsh[(n + 1) * 40 + kr] = f2h(f.y);
                Wsh[(n + 2) * 40 + kr] = f2h(f.z);
                Wsh[(n + 3) * 40 + kr] = f2h(f.w);
            }
        }
        __syncthreads();

        f16x8 af[4], bf[4];
        for (int mi = 0; mi < 4; mi++)
            af[mi] = *(const f16x8*)&Ash[(wm + mi * 16 + l15) * 40 + quad * 8];
        for (int ni = 0; ni < 4; ni++)
            bf[ni] = *(const f16x8*)&Wsh[(wn + ni * 16 + l15) * 40 + quad * 8];
        for (int mi = 0; mi < 4; mi++)
            for (int ni = 0; ni < 4; ni++)
                acc[mi][ni] = __builtin_amdgcn_mfma_f32_16x16x32_f16(
                    af[mi], bf[ni], acc[mi][ni], 0, 0, 0);
    }

    // Epilogue: C/D layout col = lane&15, row = quad*4 + reg; store fp16
    for (int mi = 0; mi < 4; mi++)
        for (int ni = 0; ni < 4; ni++)
            for (int r = 0; r < 4; r++) {
                const int row = m0 + wm + mi * 16 + quad * 4 + r;
                const int col = n0 + wn + ni * 16 + l15;
                const u16 hv = f2h(acc[mi][ni][r]);
                if (which == 0)      Qf[(size_t)row * DD + col] = hv;
                else if (which == 1) Kf[(size_t)row * DD + col] = hv;
                else                 VT[(size_t)col * NN + row] = hv;
            }
}

// ---------------------------------------------------------------------------
// Flash attention partials — depth-2 async pipeline on a 4x16KB LDS ring,
// XCD-pinned work claiming (kept from R6: FETCH 595->153MB).
// 8 phases per 64-j tile: p0-3 QK on K d-quarters, p4-7 PV on V d-quarters.
// Phase p: issue DMA for phase p+2's region; compute on region staged at
// p-2; PIPE_BAR waits only the (p+1) DMA group -> newest group stays in
// flight across the barrier (the thing __syncthreads structurally forbids).
// Region recycling is 2-barrier separated by construction.
// ---------------------------------------------------------------------------
__global__ __launch_bounds__(256, 2)
void attn_kernel(const u16* __restrict__ Qf, const u16* __restrict__ Kf,
                 const u16* __restrict__ VT,
                 u16* __restrict__ Opart, float* __restrict__ Mp,
                 float* __restrict__ Lp, int* __restrict__ cnt)
{
    const int tid  = threadIdx.x;
    const int lane = tid & 63;
    const int wave = tid >> 6;
    const int l15  = lane & 15;
    const int quad = lane >> 4;

    __shared__ u16 KV[4][8192];         // 4 x 16KB ring
    __shared__ u16 Ps[4][16 * 68];      // per-wave P transpose
    __shared__ int sPart, sRb;

    // ---- claim work item pinned to this block's physical XCD ----
    if (tid == 0) {
        u32 xcd;
        asm volatile("s_getreg_b32 %0, hwreg(HW_REG_XCC_ID)" : "=s"(xcd));
        xcd &= 7;
        int part = -1, rb = 0;
        for (int t = 0; t < 8; t++) {
            const int p = (xcd + t) & 7;
            const int idx = atomicAdd(&cnt[p], 1);
            if (idx < RB_PER_PART) { part = p; rb = idx; break; }
        }
        sPart = part; sRb = rb;
    }
    __syncthreads();
    const int part = sPart;
    const int rb   = sRb;
    if (part < 0) return;               // unreachable (pigeonhole)

    const int q0 = rb * 64 + wave * 16;

    // Q resident: 16 A-fragments (full D=512) — loaded before any DMA so the
    // preamble vmcnt accounting stays simple (oldest-first drain).
    f16x8 qf[16];
    for (int kk = 0; kk < 16; kk++)
        qf[kk] = *(const f16x8*)&Qf[(size_t)(q0 + l15) * DD + kk * 32 + quad * 8];

    floatx4 o[32] = {};
    float m_run[4], l_run[4];
    for (int r = 0; r < 4; r++) { m_run[r] = -1e30f; l_run[r] = 0.f; }

    const int j_begin = part * JCHUNK;
    const int j_end   = j_begin + JCHUNK;

    // --- staging: 4 async16/wave per call = 16KB/block ---
    const int krow4  = lane >> 4;        // K: row-sub 0..3
    const int kpos16 = lane & 15;        // K: chunk pos in row (of 16)
    const int vrs    = lane >> 3;        // V: row-sub 0..7
    const int vch    = (lane & 7) ^ vrs; // V: swizzled source chunk

    // K quarter: 64 j-rows x 128 d (d-quarter dq), row stride 128 u16
    auto stageKq = [&](int dq, int j0, int rg) {
        for (int c = 0; c < 4; c++) {
            const int jj  = wave * 16 + c * 4;
            const int row = jj + krow4;
            const int sch = kpos16 ^ (row & 7);
            async16(&Kf[(size_t)(j0 + row) * DD + dq * 128 + sch * 8],
                    &KV[rg][jj * 128]);
        }
    };
    // V quarter: 128 d-rows (quarter dq) x 64 j, row stride 64 u16
    auto stageVq = [&](int dq, int j0, int rg) {
        for (int c = 0; c < 4; c++) {
            const int dl = wave * 32 + c * 8;
            async16(&VT[(size_t)(dq * 128 + dl + vrs) * NN + j0 + vch * 8],
                    &KV[rg][dl * 64]);
        }
    };

    // QK quarter: 16 ds_read_b128 + 16 MFMA
    auto qkQ = [&](int rg, int dq, floatx4* s) {
        for (int k8 = 0; k8 < 4; k8++)
            for (int nt = 0; nt < 4; nt++) {
                const int row = nt * 16 + l15;
                const int ch  = (k8 * 4 + quad) ^ (l15 & 7);
                f16x8 b = *(const f16x8*)&KV[rg][row * 128 + ch * 8];
                s[nt] = __builtin_amdgcn_mfma_f32_16x16x32_f16(qf[dq * 4 + k8], b, s[nt], 0, 0, 0);
            }
    };
    // PV quarter: 16 ds_read_b128 + 16 MFMA
    auto pvQ = [&](int rg, int dq, f16x8* pf) {
        for (int t = 0; t < 8; t++) {
            const int row = t * 16 + l15;
            const int c0  = quad ^ (l15 & 7);
            const int c1  = (4 + quad) ^ (l15 & 7);
            f16x8 b0 = *(const f16x8*)&KV[rg][row * 64 + c0 * 8];
            f16x8 b1 = *(const f16x8*)&KV[rg][row * 64 + c1 * 8];
            o[dq * 8 + t] = __builtin_amdgcn_mfma_f32_16x16x32_f16(pf[0], b0, o[dq * 8 + t], 0, 0, 0);
            o[dq * 8 + t] = __builtin_amdgcn_mfma_f32_16x16x32_f16(pf[1], b1, o[dq * 8 + t], 0, 0, 0);
        }
    };

    // preamble: stage K d0->R0, K d1->R1; wait d0 group only
    stageKq(0, j_begin, 0);
    stageKq(1, j_begin, 1);
    PIPE_BAR();

    for (int j0 = j_begin; j0 < j_end; j0 += 64) {
        const int jn = (j0 + 64 < j_end) ? j0 + 64 : j_begin;  // wrap: uniform count
        floatx4 s[4] = {};

        stageKq(2, j0, 2); qkQ(0, 0, s); PIPE_BAR();           // p0
        stageKq(3, j0, 3); qkQ(1, 1, s); PIPE_BAR();           // p1
        stageVq(0, j0, 0); qkQ(2, 2, s); PIPE_BAR();           // p2
        stageVq(1, j0, 1); qkQ(3, 3, s);                       // p3 (barrier after softmax)

        // ---- leaky_relu + online softmax (unchanged math order) ----
        for (int nt = 0; nt < 4; nt++)
            for (int r = 0; r < 4; r++) {
                float x = s[nt][r];
                s[nt][r] = x >= 0.f ? x : 0.01f * x;
            }
        float mt[4];
        for (int r = 0; r < 4; r++)
            mt[r] = fmaxf(fmaxf(s[0][r], s[1][r]), fmaxf(s[2][r], s[3][r]));
        for (int off = 1; off < 16; off <<= 1)
            for (int r = 0; r < 4; r++)
                mt[r] = fmaxf(mt[r], __shfl_xor(mt[r], off));

        float alpha[4];
        for (int r = 0; r < 4; r++) {
            const float mnew = fmaxf(m_run[r], mt[r]);
            alpha[r] = __expf(m_run[r] - mnew);
            m_run[r] = mnew;
        }
        float ls[4] = {0.f, 0.f, 0.f, 0.f};
        u16 pv[4][4];
        for (int nt = 0; nt < 4; nt++)
            for (int r = 0; r < 4; r++) {
                const float p = __expf(s[nt][r] - m_run[r]);
                ls[r] += p;
                pv[nt][r] = f2h(p);
            }
        for (int off = 1; off < 16; off <<= 1)
            for (int r = 0; r < 4; r++)
                ls[r] += __shfl_xor(ls[r], off);
        for (int r = 0; r < 4; r++)
            l_run[r] = l_run[r] * alpha[r] + ls[r];
        const bool need = (alpha[0] != 1.f) | (alpha[1] != 1.f) |
                          (alpha[2] != 1.f) | (alpha[3] != 1.f);
        if (__any(need))
            for (int i = 0; i < 32; i++)
                for (int r = 0; r < 4; r++)
                    o[i][r] *= alpha[r];

        // P: C-layout -> A-layout via per-wave LDS (same-wave, lgkm only)
        for (int nt = 0; nt < 4; nt++)
            for (int r = 0; r < 4; r++)
                Ps[wave][(quad * 4 + r) * 68 + nt * 16 + l15] = pv[nt][r];
        asm volatile("s_waitcnt lgkmcnt(0)" ::: "memory");
        f16x8 pf[2];
        for (int ks = 0; ks < 2; ks++)
            pf[ks] = *(const f16x8*)&Ps[wave][l15 * 68 + ks * 32 + quad * 8];
        PIPE_BAR();                                            // end p3

        stageVq(2, j0, 2); pvQ(0, 0, pf); PIPE_BAR();          // p4
        stageVq(3, j0, 3); pvQ(1, 1, pf); PIPE_BAR();          // p5
        stageKq(0, jn, 0); pvQ(2, 2, pf); PIPE_BAR();          // p6
        stageKq(1, jn, 1); pvQ(3, 3, pf); PIPE_BAR();          // p7
    }

    // drain remaining DMA before epilogue / endpgm (LDS gets reassigned)
    asm volatile("s_waitcnt vmcnt(0)" ::: "memory");

    // ---- write partials (fp16 un-normalized O + fp32 m,l) ----
    for (int i = 0; i < 32; i++)
        for (int r = 0; r < 4; r++) {
            const int row = q0 + quad * 4 + r;
            const int col = i * 16 + l15;
            Opart[((size_t)part * NN + row) * DD + col] = f2h(o[i][r]);
        }
    if (l15 == 0)
        for (int r = 0; r < 4; r++) {
            const int row = q0 + quad * 4 + r;
            Mp[part * NN + row] = m_run[r];
            Lp[part * NN + row] = l_run[r];
        }
}

// ---------------------------------------------------------------------------
// Combine NPARTS j-partials: out = sum_p w_p O_p / sum_p w_p l_p
// ---------------------------------------------------------------------------
__global__ __launch_bounds__(256)
void combine_kernel(const u16* __restrict__ Opart, const float* __restrict__ Mp,
                    const float* __restrict__ Lp, float* __restrict__ out)
{
    const int row = blockIdx.x;
    const int tid = threadIdx.x;
    float m[NPARTS], l[NPARTS];
    float M = -1e30f;
    for (int p = 0; p < NPARTS; p++) {
        m[p] = Mp[p * NN + row];
        l[p] = Lp[p * NN + row];
        M = fmaxf(M, m[p]);
    }
    float w[NPARTS], L = 0.f;
    for (int p = 0; p < NPARTS; p++) { w[p] = __expf(m[p] - M); L += w[p] * l[p]; }
    const float inv = 1.f / L;
    for (int d = tid; d < DD; d += 256) {
        float acc = 0.f;
        for (int p = 0; p < NPARTS; p++)
            acc += w[p] * h2f(Opart[((size_t)p * NN + row) * DD + d]);
        out[(size_t)row * DD + d] = acc * inv;
    }
}

// ---------------------------------------------------------------------------
extern "C" void kernel_launch(void* const* d_in, const int* in_sizes, int n_in,
                              void* d_out, int out_size, void* d_ws, size_t ws_size,
                              hipStream_t stream)
{
    const float* x1 = (const float*)d_in[0];
    const float* x2 = (const float*)d_in[1];
    const float* qw = (const float*)d_in[2];
    const float* kw = (const float*)d_in[3];
    const float* vw = (const float*)d_in[4];
    float* out = (float*)d_out;

    // workspace: Qf|Kf|VT (8MB each fp16) | Opart 64MB fp16 | Mp | Lp | cnt[8]
    u16* Qf = (u16*)d_ws;
    u16* Kf = Qf + (size_t)NN * DD;
    u16* VT = Kf + (size_t)NN * DD;
    u16* Opart = VT + (size_t)NN * DD;
    float* Mp = (float*)(Opart + (size_t)NPARTS * NN * DD);
    float* Lp = Mp + NPARTS * NN;
    int* cnt = (int*)(Lp + NPARTS * NN);

    hipMemsetAsync(cnt, 0, NPARTS * sizeof(int), stream);
    proj_kernel<<<dim3(64, 4, 3), 256, 0, stream>>>(x1, x2, qw, kw, vw, Qf, Kf, VT);
    attn_kernel<<<dim3(RB_PER_PART * NPARTS), 256, 0, stream>>>(Qf, Kf, VT, Opart, Mp, Lp, cnt);
    combine_kernel<<<NN, 256, 0, stream>>>(Opart, Mp, Lp, out);
}